// Round 1
// baseline (377.181 us; speedup 1.0000x reference)
//
#include <hip/hip_runtime.h>
#include <math.h>

typedef __bf16 bf16x8 __attribute__((ext_vector_type(8)));
typedef __bf16 bf16x4 __attribute__((ext_vector_type(4)));
typedef float  f32x4  __attribute__((ext_vector_type(4)));

#define QL    32
#define DL    256
#define DIM   256
#define NK    21
#define KSOFT 20
#define STR   264                 // LDS row stride in bf16 elems (256 + 8 pad)
#define L2E   1.4426950408889634f // log2(e)

// One block per batch item; 256 threads = 4 waves.
// Wave w -> C-subtile (qt = w>>1, dt = w&1) of the 32x32 doc-tile sim matrix.
__global__ __launch_bounds__(256, 2)
void knrm_kernel(const int* __restrict__ q1t, const int* __restrict__ d1t,
                 const int* __restrict__ q2t, const int* __restrict__ d2t,
                 const float* __restrict__ emb,
                 const float* __restrict__ W0, const float* __restrict__ b0,
                 const float* __restrict__ W1, const float* __restrict__ b1,
                 const float* __restrict__ W2, const float* __restrict__ b2,
                 float* __restrict__ out)
{
    const int b    = blockIdx.x;
    const int tid  = threadIdx.x;
    const int wave = tid >> 6;
    const int lane = tid & 63;
    const int qt   = wave >> 1;   // 0..1 : which 16-row q subtile
    const int dt   = wave & 1;    // 0..1 : which 16-col d subtile
    const int g    = lane >> 4;   // 0..3 : k-chunk group (also C row group)
    const int cl   = lane & 15;   // 0..15

    __shared__ __align__(16) __bf16 qbuf[QL * STR];
    __shared__ __align__(16) __bf16 dbuf[32 * STR];
    __shared__ float Sqk[QL * NK];
    __shared__ int   dtok_s[DL];
    __shared__ int   qtok_s[QL];
    __shared__ float km[NK];
    __shared__ float h0[10];
    __shared__ float h1[5];
    __shared__ float logit[2];

    for (int pair = 0; pair < 2; ++pair) {
        const int* qtok = pair ? q2t : q1t;
        const int* dtok = pair ? d2t : d1t;

        if (tid < QL) qtok_s[tid] = qtok[b * QL + tid];
        dtok_s[tid] = dtok[b * DL + tid];
        for (int e = tid; e < QL * NK; e += 256) Sqk[e] = 0.0f;
        if (tid < NK) km[tid] = 0.0f;
        __syncthreads();

        // ---- stage + fp32-normalize query rows into bf16 LDS (wave w: rows w*8..w*8+7)
        #pragma unroll
        for (int i = 0; i < 8; ++i) {
            int row = wave * 8 + i;
            int tok = qtok_s[row];
            const float4* rp = reinterpret_cast<const float4*>(emb + (size_t)tok * DIM);
            float4 v = rp[lane];
            float s = v.x*v.x + v.y*v.y + v.z*v.z + v.w*v.w;
            #pragma unroll
            for (int m = 32; m; m >>= 1) s += __shfl_xor(s, m);
            float inv = rsqrtf(fmaxf(s, 1e-16f));   // norm ~16, eps never binds
            bf16x4 o;
            o[0] = (__bf16)(v.x * inv);
            o[1] = (__bf16)(v.y * inv);
            o[2] = (__bf16)(v.z * inv);
            o[3] = (__bf16)(v.w * inv);
            *reinterpret_cast<bf16x4*>(&qbuf[row * STR + lane * 4]) = o;
        }

        int qtk[4];
        #pragma unroll
        for (int i = 0; i < 4; ++i) qtk[i] = qtok_s[qt * 16 + g * 4 + i];

        float acc[4 * NK];
        #pragma unroll
        for (int e = 0; e < 4 * NK; ++e) acc[e] = 0.0f;

        for (int tile = 0; tile < 8; ++tile) {
            // ---- stage + normalize 32 doc rows (covers pair-start qbuf writes via barrier below)
            #pragma unroll
            for (int i = 0; i < 8; ++i) {
                int r = wave * 8 + i;
                int tok = dtok_s[tile * 32 + r];
                const float4* rp = reinterpret_cast<const float4*>(emb + (size_t)tok * DIM);
                float4 v = rp[lane];
                float s = v.x*v.x + v.y*v.y + v.z*v.z + v.w*v.w;
                #pragma unroll
                for (int m = 32; m; m >>= 1) s += __shfl_xor(s, m);
                float inv = rsqrtf(fmaxf(s, 1e-16f));
                bf16x4 o;
                o[0] = (__bf16)(v.x * inv);
                o[1] = (__bf16)(v.y * inv);
                o[2] = (__bf16)(v.z * inv);
                o[3] = (__bf16)(v.w * inv);
                *reinterpret_cast<bf16x4*>(&dbuf[r * STR + lane * 4]) = o;
            }
            __syncthreads();

            // ---- 16x16 MFMA over K=256 (A: lane holds q[qt*16+cl][ks*32+g*8 ..+7])
            f32x4 cf = {0.0f, 0.0f, 0.0f, 0.0f};
            #pragma unroll
            for (int ks = 0; ks < 8; ++ks) {
                bf16x8 af  = *reinterpret_cast<const bf16x8*>(&qbuf[(qt*16 + cl)*STR + ks*32 + g*8]);
                bf16x8 bfr = *reinterpret_cast<const bf16x8*>(&dbuf[(dt*16 + cl)*STR + ks*32 + g*8]);
                cf = __builtin_amdgcn_mfma_f32_16x16x32_bf16(af, bfr, cf, 0, 0, 0);
            }

            // ---- Gaussian kernels straight off the C fragment:
            // C[reg i] is mm for q-row qt*16+g*4+i, d-col tile*32+dt*16+cl
            int dtk = dtok_s[tile*32 + dt*16 + cl];
            #pragma unroll
            for (int i = 0; i < 4; ++i) {
                float mm  = cf[i];
                float mm2 = mm * mm;
                #pragma unroll
                for (int k = 0; k < KSOFT; ++k) {
                    float mu = -0.95f + 0.1f * (float)k;          // compile-time
                    float a1 = 100.0f * L2E * mu;
                    float a0 = -50.0f * L2E * mu * mu;
                    float arg = fmaf(a1, mm, fmaf(-50.0f * L2E, mm2, a0));
                    acc[i*NK + k] += exp2f(arg);
                }
                // exact kernel (sigma=0.001): == 1[token match]; integer compare
                // dodges bf16 mm noise (non-matches have |mm| < ~0.4).
                acc[i*NK + KSOFT] += (dtk == qtk[i]) ? 1.0f : 0.0f;
            }
            __syncthreads();   // protect dbuf for next tile
        }

        // ---- flush per-lane partial sums (over this lane's d-cols) into Sqk
        #pragma unroll
        for (int i = 0; i < 4; ++i) {
            int row = qt*16 + g*4 + i;
            #pragma unroll
            for (int k = 0; k < NK; ++k)
                atomicAdd(&Sqk[row*NK + k], acc[i*NK + k]);
        }
        __syncthreads();

        // ---- km[k] = sum_q log1p(Sqk[q][k])
        for (int e = tid; e < QL * NK; e += 256)
            atomicAdd(&km[e % NK], log1pf(Sqk[e]));
        __syncthreads();

        // ---- tiny MLP 21 -> 10 -> 5 -> 1
        if (tid < 10) {
            float h = b0[tid];
            #pragma unroll
            for (int k = 0; k < NK; ++k) h = fmaf(km[k], W0[tid*NK + k], h);
            h0[tid] = fmaxf(h, 0.0f);
        }
        __syncthreads();
        if (tid < 5) {
            float h = b1[tid];
            #pragma unroll
            for (int j = 0; j < 10; ++j) h = fmaf(h0[j], W1[tid*10 + j], h);
            h1[tid] = fmaxf(h, 0.0f);
        }
        __syncthreads();
        if (tid == 0) {
            float l = b2[0];
            #pragma unroll
            for (int j = 0; j < 5; ++j) l = fmaf(h1[j], W2[j], l);
            logit[pair] = l;
        }
        __syncthreads();
    }

    if (tid == 0) {
        float z = logit[0] - logit[1];
        out[b] = 1.0f / (1.0f + expf(-z));
    }
}

extern "C" void kernel_launch(void* const* d_in, const int* in_sizes, int n_in,
                              void* d_out, int out_size, void* d_ws, size_t ws_size,
                              hipStream_t stream) {
    const int*   q1  = (const int*)d_in[0];
    const int*   d1  = (const int*)d_in[1];
    const int*   q2  = (const int*)d_in[2];
    const int*   d2  = (const int*)d_in[3];
    const float* emb = (const float*)d_in[4];
    const float* W0  = (const float*)d_in[5];
    const float* b0  = (const float*)d_in[6];
    const float* W1  = (const float*)d_in[7];
    const float* b1  = (const float*)d_in[8];
    const float* W2  = (const float*)d_in[9];
    const float* b2  = (const float*)d_in[10];
    float* out = (float*)d_out;

    const int B = in_sizes[0] / QL;   // 512
    knrm_kernel<<<B, 256, 0, stream>>>(q1, d1, q2, d2, emb,
                                       W0, b0, W1, b1, W2, b2, out);
}